// Round 1
// baseline (253.547 us; speedup 1.0000x reference)
//
#include <hip/hip_runtime.h>
#include <hip/hip_bf16.h>

typedef __bf16 bf16x4 __attribute__((ext_vector_type(4)));
typedef __bf16 bf16x8 __attribute__((ext_vector_type(8)));
typedef float  f32x4  __attribute__((ext_vector_type(4)));

#define MFMA16(a,b,c) __builtin_amdgcn_mfma_f32_16x16x32_bf16((a),(b),(c),0,0,0)

// TT shapes: INP_MODES [4,8,8,4], OUT_MODES [8,8,8,8], RANKS [1,8,8,8,1]
// Per (b, m0) unit:
//   step0 (VALU fp32): h0[k=(r1*8+n1)][col=(n2*4+n3)]  (64 x 32)
//   step1 (MFMA): D1[(m1*8+r2)][(n2*4+n3)] = W1[64x64] @ h0            -> h1
//   step2 (MFMA): D2[(m2*8+r3)][(n3*8+m1)] = W2[64x64] @ h1            -> h2
//   step3 (MFMA): D3[m3(pad16)][(m2*8+m1)] = W3[16x32] @ h2  -> y
// LDS layouts (per-wave private, k-contiguous per column for b-frag b128 reads):
//   h0: [col 32][k 64, stride 72]   h1: [col 32][k 64, stride 72]
//   h2: [col 64][k 32, stride 40]   (h2 overlays h0's buffer)
// MFMA facts used (measured, cdna_hip_programming.md §3):
//   A[m=lane&15][k=(lane>>4)*8+j], B[k=(lane>>4)*8+j][n=lane&15],
//   D[row=(lane>>4)*4+reg][col=lane&15]

__global__ __launch_bounds__(256) void tt_kernel(
    const float* __restrict__ x,  const float* __restrict__ c0,
    const float* __restrict__ c1, const float* __restrict__ c2,
    const float* __restrict__ c3, const float* __restrict__ bias,
    float* __restrict__ y)
{
    __shared__ __align__(16) __bf16 lds[4 * 4864];
    __shared__ float w0s[256];

    const int tid  = threadIdx.x;
    const int wid  = tid >> 6;
    const int lane = tid & 63;
    const int g    = lane >> 4;   // quad (MFMA)
    const int l    = lane & 15;
    const int c32  = lane & 31;   // step0 column (n2*4+n3)
    const int hh   = lane >> 5;   // step0 k-half

    // stage W0 (core0, 256 fp32) into LDS once
    if (tid < 256) w0s[tid] = c0[tid];
    __syncthreads();  // only barrier in the kernel

    __bf16* bufA = &lds[wid * 4864];         // h0 [32][72] , reused as h2 [64][40]
    __bf16* bufB = &lds[wid * 4864 + 2560];  // h1 [32][72]

    // ---- weight fragments in registers (loaded once, L2-hot) ----
    // W1: A1[(m1*8+r2)][(r1*8+n1)] = c1[r1][m1][r2][n1]
    // W2: A2[(m2*8+r3)][(n2*8+r2)] = c2[r2][m2][r3][n2]
    // W3: A3[m3][(n3*8+r3)]        = c3[r3][m3][0][n3]  (rows 8..15 zero)
    bf16x8 w1f[4][2], w2f[4][2], w3f;
    #pragma unroll
    for (int i = 0; i < 4; ++i) {
      #pragma unroll
      for (int t = 0; t < 2; ++t) {
        const int rowbase = (i*2 + (l>>3))*64 + (l&7)*8;  // m*64 + r*8
        const int r1 = t*4 + g;                            // k-tile quad
        #pragma unroll
        for (int j = 0; j < 8; ++j) {
          w1f[i][t][j] = (__bf16)c1[r1*512 + rowbase + j];
          w2f[i][t][j] = (__bf16)c2[j*512 + rowbase + t*4 + g];
        }
      }
    }
    #pragma unroll
    for (int j = 0; j < 8; ++j)
      w3f[j] = (l < 8) ? (__bf16)c3[j*32 + l*4 + g] : (__bf16)0.0f;

    const int gw = (blockIdx.x * blockDim.x + tid) >> 6;   // 0..4095

    for (int bb = 0; bb < 2; ++bb) {
      const int b = gw + bb * 4096;
      const float* xb = x + (size_t)b * 1024;

      // x[b] into registers: xr[n0*8+n1] = x[b][n0*256 + n1*32 + c32]
      float xr[32];
      #pragma unroll
      for (int n0 = 0; n0 < 4; ++n0)
        #pragma unroll
        for (int n1 = 0; n1 < 8; ++n1)
          xr[n0*8 + n1] = xb[n0*256 + n1*32 + c32];

      for (int m0 = 0; m0 < 8; ++m0) {
        // ---------- step 0: fp32 VALU, K=4 ----------
        // h0[k = hh*32 + q*8 + e][c32],  r1 = hh*4+q, n1 = e
        f32x4 w0v[4];
        #pragma unroll
        for (int a = 0; a < 4; ++a)
          w0v[a] = *(const f32x4*)&w0s[m0*32 + (hh*4 + a)*4];
        #pragma unroll
        for (int q = 0; q < 4; ++q) {
          bf16x8 hv;
          #pragma unroll
          for (int e = 0; e < 8; ++e) {
            float acc = w0v[q][0]*xr[e]      + w0v[q][1]*xr[8 + e]
                      + w0v[q][2]*xr[16 + e] + w0v[q][3]*xr[24 + e];
            hv[e] = (__bf16)acc;
          }
          *(bf16x8*)&bufA[c32*72 + hh*32 + q*8] = hv;
        }

        // ---------- step 1: 64x64 @ [64x32] ----------
        #pragma unroll
        for (int u = 0; u < 2; ++u) {
          f32x4 acc[4] = {};
          #pragma unroll
          for (int t = 0; t < 2; ++t) {
            bf16x8 bf = *(const bf16x8*)&bufA[(u*16 + l)*72 + t*32 + g*8];
            #pragma unroll
            for (int i = 0; i < 4; ++i)
              acc[i] = MFMA16(w1f[i][t], bf, acc[i]);
          }
          // D1 row = i*16+g*4+r = m1*8+r2 ; col = u*16+l = n2*4+n3
          // -> h1[(n3*8+m1)][(n2*8+r2)], 4 regs contiguous in k (r2 = (g&1)*4+r)
          #pragma unroll
          for (int i = 0; i < 4; ++i) {
            bf16x4 o;
            #pragma unroll
            for (int r = 0; r < 4; ++r) o[r] = (__bf16)acc[i][r];
            const int col1 = (l&3)*8 + i*2 + (g>>1);          // n3*8+m1
            const int k1   = (u*4 + (l>>2))*8 + (g&1)*4;      // n2*8+r2
            *(bf16x4*)&bufB[col1*72 + k1] = o;
          }
        }

        // ---------- step 2: 64x64 @ [64x32] ----------
        #pragma unroll
        for (int u = 0; u < 2; ++u) {
          f32x4 acc[4] = {};
          #pragma unroll
          for (int t = 0; t < 2; ++t) {
            bf16x8 bf = *(const bf16x8*)&bufB[(u*16 + l)*72 + t*32 + g*8];
            #pragma unroll
            for (int i = 0; i < 4; ++i)
              acc[i] = MFMA16(w2f[i][t], bf, acc[i]);
          }
          // D2 row = i*16+g*4+r = m2*8+r3 ; col = u*16+l = n3*8+m1
          // -> h2[(m2*8+m1)][(n3*8+r3)], 4 regs contiguous in k (r3 = (g&1)*4+r)
          #pragma unroll
          for (int i = 0; i < 4; ++i) {
            bf16x4 o;
            #pragma unroll
            for (int r = 0; r < 4; ++r) o[r] = (__bf16)acc[i][r];
            const int col3 = (i*2 + (g>>1))*8 + (l&7);        // m2*8+m1
            const int k3   = (u*2 + (l>>3))*8 + (g&1)*4;      // n3*8+r3
            *(bf16x4*)&bufA[col3*40 + k3] = o;
          }
        }

        // ---------- step 3: [16x32] @ [32x64], rows 8..15 are pad ----------
        const float* bslice = bias + m0*512;
        float* yb = y + (size_t)b*4096 + m0*512;
        #pragma unroll
        for (int u = 0; u < 4; ++u) {
          bf16x8 bf = *(const bf16x8*)&bufA[(u*16 + l)*40 + g*8];
          f32x4 acc = {};
          acc = MFMA16(w3f, bf, acc);
          // D3 row = g*4+r = m3 (valid g<2) ; col = u*16+l = m2*8+m1
          if (g < 2) {
            const int col3 = u*16 + l;
            const int off  = (col3 & 7)*64 + (col3 >> 3)*8 + g*4;  // m1*64+m2*8+m3
            f32x4 bv = *(const f32x4*)&bslice[off];
            f32x4 o  = acc + bv;
            *(f32x4*)&yb[off] = o;
          }
        }
      }
    }
}

extern "C" void kernel_launch(void* const* d_in, const int* in_sizes, int n_in,
                              void* d_out, int out_size, void* d_ws, size_t ws_size,
                              hipStream_t stream) {
    const float* x    = (const float*)d_in[0];
    const float* c0   = (const float*)d_in[1];
    const float* c1   = (const float*)d_in[2];
    const float* c2   = (const float*)d_in[3];
    const float* c3   = (const float*)d_in[4];
    const float* bias = (const float*)d_in[5];
    float* yout = (float*)d_out;
    // 1024 blocks x 256 threads = 4096 waves, 2 batch elements per wave = 8192
    tt_kernel<<<1024, 256, 0, stream>>>(x, c0, c1, c2, c3, bias, yout);
}